// Round 14
// baseline (40.795 us; speedup 1.0000x reference)
//
#include <hip/hip_runtime.h>
#include <hip/hip_bf16.h>
#include <math.h>

#define BS 8192
#define D 128
#define NROWS 16384               // 2*BS
#define COLS_PER_BLOCK 512
#define NCHUNK (COLS_PER_BLOCK / 16)      // 32 col-chunks of 16
#define NSPLIT (NROWS / COLS_PER_BLOCK)   // 32 col-splits
#define NPART NSPLIT                      // 32 partial buffers

typedef int i32x8 __attribute__((ext_vector_type(8)));
typedef float f32x4 __attribute__((ext_vector_type(4)));

#define LN2F 0.6931471805599453f
// store scale: elements written as x * 2^4 * sqrt(log2e) / ||row||; HW E8M0
// scale 2^-4 on A and B restores acc = sim * log2e exactly (powers of 2).
#define STORE_SCALE 19.217958569050494f   // 16 * 1.2011224087864498
#define E8M0_M4 123                       // 2^(123-127) = 2^-4

#if __has_builtin(__builtin_amdgcn_exp2f)
#define EXP2F(x) __builtin_amdgcn_exp2f(x)
#else
#define EXP2F(x) exp2f(x)
#endif

// Layout of catF (fp8, "16-row-group tiled"): byte addr of (row, k) =
//   (row>>4)*2048 + (k>>5)*512 + (row&15)*32 + (k&31)
// -> a 16-row x K=128 group is one contiguous 2 KiB cell; an MFMA fragment
//    (lanes: l15=row/col, l4=k-block-of-32) is lane 32B at l4*512+l15*32 —
//    the wave's 64x32B = the whole 2 KiB cell, fully coalesced.

// Kernel 1: row norms + scaled fp8(e4m3) conversion into catF.
__global__ __launch_bounds__(256) void nrm_cvt(const float* __restrict__ f,
                                               const float* __restrict__ noise,
                                               char* __restrict__ catF) {
  const int lane = threadIdx.x & 63;
  const int wv = threadIdx.x >> 6;
  const int row = blockIdx.x * 4 + wv;
  const float* src = (row < BS) ? (noise + (size_t)row * D) : (f + (size_t)(row - BS) * D);
  float2 v = ((const float2*)src)[lane];   // k = 2*lane, 2*lane+1 (same 32-cell)
  float ss = v.x * v.x + v.y * v.y;
#pragma unroll
  for (int m = 1; m <= 32; m <<= 1) ss += __shfl_xor(ss, m, 64);
  const float s = STORE_SCALE / sqrtf(ss);
  // pack 2 floats -> 2 OCP e4m3 bytes (low 16 bits)
  const int packed = __builtin_amdgcn_cvt_pk_fp8_f32(v.x * s, v.y * s, 0, false);
  char* dst = catF + ((size_t)(row >> 4) << 11) + ((lane >> 4) << 9) +
              ((row & 15) << 5) + ((lane & 15) << 1);
  *(unsigned short*)dst = (unsigned short)(packed & 0xffff);
}

// Kernel 2: fused GEMM + exp2 + row-sum, MX-FP8 K=128 + DEPTH-3 REGISTER
// PREFETCH RING: fp8 makes a B chunk only 8 VGPRs, so a 4-slot ring (32
// VGPRs) issues loads 3 chunks ahead (~500 issue-cyc cover vs 300-600 cyc
// L2/L3 latency). One mfma_scale_f32_16x16x128 per 16x16 tile. R8 structure
// otherwise: 4-wave blocks (waves share the B slice -> L1 dedup), no LDS,
// no barriers. Grid 32x32, 16 waves/CU.
__global__ __launch_bounds__(256) void infonce_main(
    const char* __restrict__ catF,
    float* __restrict__ ws_neg, float* __restrict__ ws_pos) {
  const int tid = threadIdx.x;
  const int lane = tid & 63;
  const int w = tid >> 6;
  const int l15 = lane & 15, l4 = lane >> 4;
  const int nb = blockIdx.x, mb = blockIdx.y;
  const int growbase = mb * 256 + w * 64;
  const int col0 = nb * COLS_PER_BLOCK;
  const int lbase = l4 * 512 + l15 * 32;

  // A fragments: 64 f-rows x K=128 fp8 (32 VGPRs total)
  i32x8 a[4];
  {
    const char* ab = catF + ((size_t)((BS + growbase) >> 4) << 11) + lbase;
#pragma unroll
    for (int rf = 0; rf < 4; rf++) a[rf] = *(const i32x8*)(ab + rf * 2048);
  }

  f32x4 rs[4];
  const f32x4 z = {0.f, 0.f, 0.f, 0.f};
#pragma unroll
  for (int rf = 0; rf < 4; rf++) rs[rf] = z;

  const char* bl = catF + ((size_t)(col0 >> 4) << 11) + lbase;

  // 4-slot register ring, prefetch depth 3
  i32x8 bb[4];
  bb[0] = *(const i32x8*)(bl);
  bb[1] = *(const i32x8*)(bl + 2048);
  bb[2] = *(const i32x8*)(bl + 4096);

#pragma unroll
  for (int ch = 0; ch < NCHUNK; ++ch) {
    const int cu = ch & 3;  // compile-time under full unroll
    if (ch + 3 < NCHUNK)
      bb[(ch + 3) & 3] = *(const i32x8*)(bl + (size_t)(ch + 3) * 2048);

    f32x4 acc[4];
#pragma unroll
    for (int rf = 0; rf < 4; rf++)
      acc[rf] = __builtin_amdgcn_mfma_scale_f32_16x16x128_f8f6f4(
          a[rf], bb[cu], z, 0 /*A=fp8*/, 0 /*B=fp8*/,
          0, E8M0_M4, 0, E8M0_M4);

    // epilogue: acc = sim*log2e -> exp2, accumulate row sums, excise diagonals.
    const int c0 = col0 + ch * 16;
    const bool dPos = ((c0 & ~63) == growbase);          // cols == f-row ids
    const bool dSelf = (((c0 - BS) & ~63) == growbase);  // cols == i+bs
    if (!dPos && !dSelf) {
#pragma unroll
      for (int rf = 0; rf < 4; rf++) {
        f32x4 e;
#pragma unroll
        for (int r = 0; r < 4; r++) e[r] = EXP2F(acc[rf][r]);
        rs[rf] += e;  // f32x4 add -> v_pk_add_f32 pair
      }
    } else {
#pragma unroll
      for (int rf = 0; rf < 4; rf++)
#pragma unroll
        for (int r = 0; r < 4; r++) {
          const int grow = growbase + rf * 16 + l4 * 4 + r;
          const int gcol = c0 + l15;
          const float v = acc[rf][r];
          const bool ex = dPos ? (gcol == grow) : (gcol == grow + BS);
          if (dPos && gcol == grow) ws_pos[grow] = v;  // sim_pos * log2e
          rs[rf][r] += ex ? 0.f : EXP2F(v);
        }
    }
  }

  // reduce rowsums across the 16 lanes (l15) sharing each row
  float rowsum[16];
#pragma unroll
  for (int rf = 0; rf < 4; rf++)
#pragma unroll
    for (int r = 0; r < 4; r++) {
      float v = rs[rf][r];
      v += __shfl_xor(v, 1, 64);
      v += __shfl_xor(v, 2, 64);
      v += __shfl_xor(v, 4, 64);
      v += __shfl_xor(v, 8, 64);
      rowsum[rf * 4 + r] = v;
    }
  if (l15 == 0) {
    float* dst = ws_neg + (size_t)nb * BS + growbase;
#pragma unroll
    for (int rf = 0; rf < 4; rf++)
#pragma unroll
      for (int r = 0; r < 4; r++) dst[rf * 16 + l4 * 4 + r] = rowsum[rf * 4 + r];
  }
}

// Kernel 3a: per-row loss, 32-block partial sums.
__global__ __launch_bounds__(256) void finalize1(const float* __restrict__ ws_neg,
                                                 const float* __restrict__ ws_pos,
                                                 float* __restrict__ partial) {
  const int row = blockIdx.x * 256 + threadIdx.x;
  float neg = 0.f;
#pragma unroll
  for (int p = 0; p < NPART; p++) neg += ws_neg[(size_t)p * BS + row];
  // loss = log(neg_sum + eps) - sim_pos ; sim_pos = (sim*log2e)*ln2
  float local = logf(neg + 1e-6f) - ws_pos[row] * LN2F;
#pragma unroll
  for (int m = 1; m <= 32; m <<= 1) local += __shfl_xor(local, m, 64);
  __shared__ float red[4];
  if ((threadIdx.x & 63) == 0) red[threadIdx.x >> 6] = local;
  __syncthreads();
  if (threadIdx.x == 0) partial[blockIdx.x] = red[0] + red[1] + red[2] + red[3];
}

// Kernel 3b: final mean over the 32 block partials.
__global__ void finalize2(const float* __restrict__ partial, float* __restrict__ out) {
  float v = ((int)threadIdx.x < 32) ? partial[threadIdx.x] : 0.f;
#pragma unroll
  for (int m = 1; m <= 32; m <<= 1) v += __shfl_xor(v, m, 64);
  if (threadIdx.x == 0) out[0] = v * (1.f / BS);
}

extern "C" void kernel_launch(void* const* d_in, const int* in_sizes, int n_in,
                              void* d_out, int out_size, void* d_ws, size_t ws_size,
                              hipStream_t stream) {
  const float* f = (const float*)d_in[0];
  const float* noise = (const float*)d_in[1];
  char* ws = (char*)d_ws;
  char* catF = ws;                                       // 2 MiB (fp8 tiled)
  float* ws_pos = (float*)(ws + (size_t)NROWS * D);      // 32 KiB
  float* ws_neg = ws_pos + BS;                           // 1 MiB
  float* partial = ws_neg + (size_t)NPART * BS;          // 128 B

  nrm_cvt<<<NROWS / 4, 256, 0, stream>>>(f, noise, catF);
  dim3 grid(NSPLIT, BS / 256);                           // 32 x 32 = 1024 blocks
  infonce_main<<<grid, 256, 0, stream>>>(catF, ws_neg, ws_pos);
  finalize1<<<BS / 256, 256, 0, stream>>>(ws_neg, ws_pos, partial);
  finalize2<<<1, 64, 0, stream>>>(partial, (float*)d_out);
}